// Round 1
// baseline (647.937 us; speedup 1.0000x reference)
//
#include <hip/hip_runtime.h>

// ---------------------------------------------------------------------------
// QueryConditionedTransportScorerV3 on MI355X (gfx950)
// Q=64 W=16 A=64 D=H=512.  Decomposition:
//   fused@rw1 = Ya[w,a] + Yq[q] + [a*q ; |a-q|+c] @ rw1[1024:2048]  (MFMA bf16)
//   h = rstd*(sum - mu*S1) + (rb1 + rb@rw1); gelu; @rw2; softmax+entropy fused
// ---------------------------------------------------------------------------

#define DEV static __device__ __forceinline__

typedef __attribute__((ext_vector_type(8))) __bf16 bf16x8;
typedef __attribute__((ext_vector_type(4))) float f32x4;

DEV unsigned short f2bf(float f) {
  unsigned u = __builtin_bit_cast(unsigned, f);
  u = (u + 0x7fffu + ((u >> 16) & 1u)) >> 16;
  return (unsigned short)u;
}

DEV float gelu_exact(float x) {
  return 0.5f * x * (1.0f + erff(x * 0.70710678118654752f));
}

// ---------------- transpose + bf16-convert rw1 rows 1024..2047 --------------
// WT[n][k2] = rg[1024+k2] * rw1[1024+k2][n],  n in [0,512), k2 in [0,1024)
__global__ __launch_bounds__(256) void wt_kernel(const float* __restrict__ rw1,
                                                 const float* __restrict__ rg,
                                                 unsigned short* __restrict__ WT) {
  __shared__ float t[64][65];
  const int tid = threadIdx.x;
  const int kt = (blockIdx.x >> 3) << 6;   // 16 k-tiles
  const int ct = (blockIdx.x & 7) << 6;    // 8 n-tiles
  for (int idx = tid; idx < 4096; idx += 256) {
    const int r = idx >> 6, c = idx & 63;
    t[r][c] = rg[1024 + kt + r] * rw1[(1024 + kt + r) * 512 + ct + c];
  }
  __syncthreads();
  for (int idx = tid; idx < 4096; idx += 256) {
    const int c = idx >> 6, r = idx & 63;
    WT[(ct + c) * 1024 + kt + r] = f2bf(t[r][c]);
  }
}

// ------------- S1[n] = sum_k rg[k]*rw1[k][n];  B1[n] = sum_k rb[k]*rw1[k][n]
__global__ __launch_bounds__(512) void s1b1_kernel(const float* __restrict__ rw1,
                                                   const float* __restrict__ rg,
                                                   const float* __restrict__ rb,
                                                   float* __restrict__ S1,
                                                   float* __restrict__ B1) {
  const int n = threadIdx.x;            // 512 threads = all n
  const int kc = blockIdx.x << 7;       // 16 blocks x 128 k
  float s = 0.f, bb = 0.f;
  for (int k = kc; k < kc + 128; ++k) {
    const float wv = rw1[(k << 9) + n];
    s += rg[k] * wv;
    bb += rb[k] * wv;
  }
  atomicAdd(&S1[n], s);
  atomicAdd(&B1[n], bb);
}

// ---------------- mass-weighted pooling of query atoms ----------------------
__global__ __launch_bounds__(256) void pool_kernel(const float* __restrict__ qa,
                                                   const float* __restrict__ qm,
                                                   float* __restrict__ pooled) {
  const int q = blockIdx.x, tid = threadIdx.x;
  __shared__ float qms[64];
  __shared__ float sinv;
  if (tid < 64) {
    float m = fmaxf(qm[(q << 6) + tid], 0.f);
    qms[tid] = m;
    float s = m;
#pragma unroll
    for (int off = 1; off < 64; off <<= 1) s += __shfl_xor(s, off);
    if (tid == 0) sinv = 1.0f / fmaxf(s, 1e-8f);
  }
  __syncthreads();
  for (int d = tid; d < 512; d += 256) {
    float acc = 0.f;
#pragma unroll 8
    for (int a = 0; a < 64; ++a) acc += qms[a] * qa[(((q << 6) + a) << 9) + d];
    pooled[(q << 9) + d] = acc * sinv;
  }
}

// ------------- generic LN -> Linear -> GELU -> Linear, 4 rows/block ---------
__global__ __launch_bounds__(256) void mlp4_kernel(
    const float* __restrict__ x1, const float* __restrict__ x2,
    const float* __restrict__ g, const float* __restrict__ b,
    const float* __restrict__ w1, const float* __restrict__ b1,
    const float* __restrict__ w2, const float* __restrict__ b2,
    float* __restrict__ out, const int kshift) {
  __shared__ float xT[4096];            // [k][4 rows], max din=1024
  const int tid = threadIdx.x;
  const int row0 = blockIdx.x << 2;
  const int din = 1 << kshift;
  const int dh = din >> 1;

  for (int idx = tid; idx < (din << 2); idx += 256) {
    const int r = idx >> kshift, k = idx & (din - 1);
    float v;
    if (x2 != nullptr) {
      v = (k < dh) ? x1[(row0 + r) * dh + k] : x2[(row0 + r) * dh + (k - dh)];
    } else {
      v = x1[(row0 + r) * din + k];
    }
    xT[(k << 2) + r] = v;
  }
  __syncthreads();

  // LayerNorm: wave v handles row v
  {
    const int wv = tid >> 6, lane = tid & 63;
    float s = 0.f, ss = 0.f;
    for (int k = lane; k < din; k += 64) {
      const float v = xT[(k << 2) + wv];
      s += v; ss += v * v;
    }
#pragma unroll
    for (int off = 1; off < 64; off <<= 1) {
      s += __shfl_xor(s, off); ss += __shfl_xor(ss, off);
    }
    const float inv = 1.0f / (float)din;
    const float mu = s * inv;
    const float var = ss * inv - mu * mu;
    const float rstd = rsqrtf(var + 1e-5f);
    for (int k = lane; k < din; k += 64) {
      const int ix = (k << 2) + wv;
      xT[ix] = (xT[ix] - mu) * rstd * g[k] + b[k];
    }
  }
  __syncthreads();

  const int c0 = tid, c1 = tid + 256;
  float aA[4] = {0, 0, 0, 0}, aB[4] = {0, 0, 0, 0};
  for (int k = 0; k < din; ++k) {
    const float4 xv = *(const float4*)(xT + (k << 2));
    const float wa = w1[(k << 9) + c0];
    const float wb = w1[(k << 9) + c1];
    aA[0] += xv.x * wa; aA[1] += xv.y * wa; aA[2] += xv.z * wa; aA[3] += xv.w * wa;
    aB[0] += xv.x * wb; aB[1] += xv.y * wb; aB[2] += xv.z * wb; aB[3] += xv.w * wb;
  }
  float hA[4], hB[4];
  const float biA = b1[c0], biB = b1[c1];
#pragma unroll
  for (int r = 0; r < 4; ++r) {
    hA[r] = gelu_exact(aA[r] + biA);
    hB[r] = gelu_exact(aB[r] + biB);
  }
  __syncthreads();
#pragma unroll
  for (int r = 0; r < 4; ++r) {
    xT[(c0 << 2) + r] = hA[r];
    xT[(c1 << 2) + r] = hB[r];
  }
  __syncthreads();

#pragma unroll
  for (int r = 0; r < 4; ++r) { aA[r] = 0.f; aB[r] = 0.f; }
  for (int k = 0; k < 512; ++k) {
    const float4 xv = *(const float4*)(xT + (k << 2));
    const float wa = w2[(k << 9) + c0];
    const float wb = w2[(k << 9) + c1];
    aA[0] += xv.x * wa; aA[1] += xv.y * wa; aA[2] += xv.z * wa; aA[3] += xv.w * wa;
    aB[0] += xv.x * wb; aB[1] += xv.y * wb; aB[2] += xv.z * wb; aB[3] += xv.w * wb;
  }
  const float b2A = b2[c0], b2B = b2[c1];
#pragma unroll
  for (int r = 0; r < 4; ++r) {
    out[(row0 + r) * 512 + c0] = aA[r] + b2A;
    out[(row0 + r) * 512 + c1] = aB[r] + b2B;
  }
}

// ---------------- plain linear vs rg-scaled rw1 slice, 4 rows/block ---------
__global__ __launch_bounds__(256) void lin4_kernel(const float* __restrict__ x,
                                                   const float* __restrict__ w,
                                                   const float* __restrict__ rg,
                                                   const int koff,
                                                   float* __restrict__ out) {
  __shared__ float xT[2048];
  const int tid = threadIdx.x;
  const int row0 = blockIdx.x << 2;
  for (int idx = tid; idx < 2048; idx += 256) {
    const int r = idx >> 9, k = idx & 511;
    xT[(k << 2) + r] = x[((row0 + r) << 9) + k];
  }
  __syncthreads();
  const int c0 = tid, c1 = tid + 256;
  float aA[4] = {0, 0, 0, 0}, aB[4] = {0, 0, 0, 0};
  for (int k = 0; k < 512; ++k) {
    const float sc = rg[koff + k];
    const float4 xv = *(const float4*)(xT + (k << 2));
    const float wa = w[((koff + k) << 9) + c0] * sc;
    const float wb = w[((koff + k) << 9) + c1] * sc;
    aA[0] += xv.x * wa; aA[1] += xv.y * wa; aA[2] += xv.z * wa; aA[3] += xv.w * wa;
    aB[0] += xv.x * wb; aB[1] += xv.y * wb; aB[2] += xv.z * wb; aB[3] += xv.w * wb;
  }
#pragma unroll
  for (int r = 0; r < 4; ++r) {
    out[((row0 + r) << 9) + c0] = aA[r];
    out[((row0 + r) << 9) + c1] = aB[r];
  }
}

// ---------------------------- main fused kernel -----------------------------
// 1 block per (q,w): build [64 x 1024] bf16 pair-matrix in LDS (frag order),
// MFMA vs WT, fused epilogue: LN-fold + GELU + rw2-GEMV + softmax + entropy.
__global__ __launch_bounds__(512, 1) void main_kernel(
    const float* __restrict__ AH, const float* __restrict__ QH,
    const float* __restrict__ CH, const unsigned short* __restrict__ WT,
    const float* __restrict__ Ya, const float* __restrict__ Yq,
    const float* __restrict__ S1, const float* __restrict__ B1,
    const float* __restrict__ rb1, const float* __restrict__ rw2,
    const float* __restrict__ rb2, const float* __restrict__ cmass,
    float* __restrict__ out) {
  extern __shared__ char smem_raw[];
  float* qs = (float*)smem_raw;                       // 512
  float* cs = qs + 512;                               // 512
  float* mu_s = cs + 512;                             // 64
  float* rs_s = mu_s + 64;                            // 64
  float* rel_s = rs_s + 64;                           // 64
  uint4* apv = (uint4*)(smem_raw + 5120);             // 128 KB frag-order bf16

  const int tid = threadIdx.x;
  const int l = tid & 63;
  const int wv = tid >> 6;
  const int q = blockIdx.x >> 4;
  const int w = blockIdx.x & 15;

  qs[tid] = QH[(q << 9) + tid];
  cs[tid] = CH[(w << 9) + tid];
  if (tid < 64) rel_s[tid] = 0.0f;
  __syncthreads();

  // ---- build pair matrix in MFMA-fragment order:
  // frag(ks,fr,l) holds rows fr*16+(l&15), k2 = ks*32 + (l>>4)*8 + j
  {
    const int r = ((wv & 3) << 4) + (l & 15);
    const float* arow = AH + (((w << 6) + r) << 9);
    const int kh = (l >> 4) << 3;
#pragma unroll
    for (int i = 0; i < 16; ++i) {
      const int ks = (wv >> 2) + (i << 1);
      const int kb = (ks << 5) + kh;   // k2 base (multiple of 8)
      const int ka = kb & 511;
      const float4 a0 = *(const float4*)(arow + ka);
      const float4 a1 = *(const float4*)(arow + ka + 4);
      const float4 q0 = *(const float4*)(qs + ka);
      const float4 q1 = *(const float4*)(qs + ka + 4);
      float av[8] = {a0.x, a0.y, a0.z, a0.w, a1.x, a1.y, a1.z, a1.w};
      float qv[8] = {q0.x, q0.y, q0.z, q0.w, q1.x, q1.y, q1.z, q1.w};
      float vv[8];
      if (kb < 512) {        // segment: a*q
#pragma unroll
        for (int j = 0; j < 8; ++j) vv[j] = av[j] * qv[j];
      } else {               // segment: |a-q| + c
        const float4 c0 = *(const float4*)(cs + ka);
        const float4 c1 = *(const float4*)(cs + ka + 4);
        float cv[8] = {c0.x, c0.y, c0.z, c0.w, c1.x, c1.y, c1.z, c1.w};
#pragma unroll
        for (int j = 0; j < 8; ++j) vv[j] = fabsf(av[j] - qv[j]) + cv[j];
      }
      union { unsigned short us[8]; uint4 u4; } pk;
#pragma unroll
      for (int j = 0; j < 8; ++j) pk.us[j] = f2bf(vv[j]);
      apv[(ks << 8) + ((wv & 3) << 6) + l] = pk.u4;
    }
  }

  // ---- LN stats over all 2048 fused values, per row (wave wv: rows wv*8..+7)
  {
    float sq = 0.f, sqq = 0.f;
#pragma unroll
    for (int it = 0; it < 8; ++it) {
      const float v = qs[l + (it << 6)];
      sq += v; sqq += v * v;
    }
#pragma unroll
    for (int off = 1; off < 64; off <<= 1) {
      sq += __shfl_xor(sq, off); sqq += __shfl_xor(sqq, off);
    }
    for (int rr = 0; rr < 8; ++rr) {
      const int r = (wv << 3) + rr;
      const float* arow = AH + (((w << 6) + r) << 9);
      float s1v = 0.f, s2v = 0.f;
#pragma unroll
      for (int it = 0; it < 8; ++it) {
        const int k = l + (it << 6);
        const float a = arow[k], qv = qs[k], cv = cs[k];
        const float aq = a * qv;
        const float dd = fabsf(a - qv) + cv;
        s1v += a + aq + dd;
        s2v += a * a + aq * aq + dd * dd;
      }
#pragma unroll
      for (int off = 1; off < 64; off <<= 1) {
        s1v += __shfl_xor(s1v, off); s2v += __shfl_xor(s2v, off);
      }
      if (l == 0) {
        const float mu = (s1v + sq) * (1.0f / 2048.0f);
        const float var = (s2v + sqq) * (1.0f / 2048.0f) - mu * mu;
        mu_s[r] = mu;
        rs_s[r] = rsqrtf(var + 1e-5f);
      }
    }
  }
  __syncthreads();

  // ---- MFMA: 64 rows x 512 cols, K=1024; wave wv owns cols wv*64..+63
  f32x4 acc[4][4] = {};
  const int ncb = (wv << 6) + (l & 15);
  const unsigned short* wptr0 = WT + ncb * 1024 + ((l >> 4) << 3);
#pragma unroll 2
  for (int ks = 0; ks < 32; ++ks) {
    bf16x8 afr[4], bfr[4];
#pragma unroll
    for (int fr = 0; fr < 4; ++fr)
      afr[fr] = __builtin_bit_cast(bf16x8, apv[(ks << 8) + (fr << 6) + l]);
#pragma unroll
    for (int cf = 0; cf < 4; ++cf)
      bfr[cf] = __builtin_bit_cast(bf16x8, *(const uint4*)(wptr0 + (cf << 14) + (ks << 5)));
#pragma unroll
    for (int fr = 0; fr < 4; ++fr)
#pragma unroll
      for (int cf = 0; cf < 4; ++cf)
        acc[fr][cf] = __builtin_amdgcn_mfma_f32_16x16x32_bf16(afr[fr], bfr[cf], acc[fr][cf], 0, 0, 0);
  }

  // ---- epilogue: LN-fold + gelu + dot(rw2), reduce to per-row relevance
  {
    float yqv[4], s1c[4], b1c[4], w2c[4];
#pragma unroll
    for (int cf = 0; cf < 4; ++cf) {
      const int n = ncb + (cf << 4);
      yqv[cf] = Yq[(q << 9) + n];
      s1c[cf] = S1[n];
      b1c[cf] = B1[n] + rb1[n];
      w2c[cf] = rw2[n];
    }
    const int rsub = (l >> 4) << 2;
#pragma unroll
    for (int fr = 0; fr < 4; ++fr) {
#pragma unroll
      for (int j = 0; j < 4; ++j) {
        const int r = (fr << 4) + rsub + j;
        const float mu = mu_s[r], rs = rs_s[r];
        float rp = 0.f;
#pragma unroll
        for (int cf = 0; cf < 4; ++cf) {
          const int n = ncb + (cf << 4);
          const float ya = Ya[(((w << 6) + r) << 9) + n];
          const float hp = rs * (acc[fr][cf][j] + ya + yqv[cf] - mu * s1c[cf]) + b1c[cf];
          rp += gelu_exact(hp) * w2c[cf];
        }
        rp += __shfl_xor(rp, 1); rp += __shfl_xor(rp, 2);
        rp += __shfl_xor(rp, 4); rp += __shfl_xor(rp, 8);
        if ((l & 15) == 0) atomicAdd(&rel_s[r], rp);
      }
    }
  }
  __syncthreads();

  // ---- softmax over atoms + entropy (wave 0)
  if (tid < 64) {
    const float relv = rel_s[tid] + rb2[0];
    const float x = logf(fmaxf(cmass[(w << 6) + tid], 1e-8f)) + relv;
    float m = x;
#pragma unroll
    for (int off = 1; off < 64; off <<= 1) m = fmaxf(m, __shfl_xor(m, off));
    const float p = expf(x - m);
    float s = p;
#pragma unroll
    for (int off = 1; off < 64; off <<= 1) s += __shfl_xor(s, off);
    float mix = p / fmaxf(s, 1e-8f);
    float s2 = mix;
#pragma unroll
    for (int off = 1; off < 64; off <<= 1) s2 += __shfl_xor(s2, off);
    mix = mix / fmaxf(s2, 1e-8f);
    const float et = -mix * logf(fmaxf(mix, 1e-8f));
    float ent = et;
#pragma unroll
    for (int off = 1; off < 64; off <<= 1) ent += __shfl_xor(ent, off);
    out[(blockIdx.x << 6) + tid] = mix;                 // mixed[q][w][a]
    if (tid == 0) out[65536 + blockIdx.x] = ent;        // entropy[q][w]
  }
}

// ---------------------------------------------------------------------------
extern "C" void kernel_launch(void* const* d_in, const int* in_sizes, int n_in,
                              void* d_out, int out_size, void* d_ws, size_t ws_size,
                              hipStream_t stream) {
  (void)in_sizes; (void)n_in; (void)out_size; (void)ws_size;
  const float* q_atoms = (const float*)d_in[0];
  const float* q_mass  = (const float*)d_in[1];
  const float* c_atoms = (const float*)d_in[2];
  const float* c_mass  = (const float*)d_in[3];
  const float* c_sum   = (const float*)d_in[4];
  const float* e_ctx   = (const float*)d_in[5];
  const float* qg  = (const float*)d_in[6];  const float* qb  = (const float*)d_in[7];
  const float* qw1 = (const float*)d_in[8];  const float* qb1 = (const float*)d_in[9];
  const float* qw2 = (const float*)d_in[10]; const float* qb2 = (const float*)d_in[11];
  const float* ag  = (const float*)d_in[12]; const float* ab  = (const float*)d_in[13];
  const float* aw1 = (const float*)d_in[14]; const float* ab1 = (const float*)d_in[15];
  const float* aw2 = (const float*)d_in[16]; const float* ab2 = (const float*)d_in[17];
  const float* cg  = (const float*)d_in[18]; const float* cb  = (const float*)d_in[19];
  const float* cw1 = (const float*)d_in[20]; const float* cb1 = (const float*)d_in[21];
  const float* cw2 = (const float*)d_in[22]; const float* cb2 = (const float*)d_in[23];
  const float* rg  = (const float*)d_in[24]; const float* rb  = (const float*)d_in[25];
  const float* rw1 = (const float*)d_in[26]; const float* rb1 = (const float*)d_in[27];
  const float* rw2 = (const float*)d_in[28]; const float* rb2 = (const float*)d_in[29];

  float* ws = (float*)d_ws;
  float* pooled = ws;                       // 32768
  float* qh     = ws + 32768;               // 32768
  float* ahh    = ws + 65536;               // 524288
  float* chh    = ws + 589824;              // 8192
  float* Ya     = ws + 598016;              // 524288
  float* Yq     = ws + 1122304;             // 32768
  float* S1     = ws + 1155072;             // 512
  float* B1     = ws + 1155584;             // 512
  unsigned short* WT = (unsigned short*)(ws + 1156096);  // 524288 bf16 = 1 MB
  float* out = (float*)d_out;

  hipMemsetAsync(S1, 0, 1024 * sizeof(float), stream);   // S1 + B1
  wt_kernel<<<128, 256, 0, stream>>>(rw1, rg, WT);
  s1b1_kernel<<<16, 512, 0, stream>>>(rw1, rg, rb, S1, B1);
  pool_kernel<<<64, 256, 0, stream>>>(q_atoms, q_mass, pooled);
  mlp4_kernel<<<16, 256, 0, stream>>>(pooled, nullptr, qg, qb, qw1, qb1, qw2, qb2, qh, 9);
  mlp4_kernel<<<256, 256, 0, stream>>>(c_atoms, nullptr, ag, ab, aw1, ab1, aw2, ab2, ahh, 9);
  mlp4_kernel<<<4, 256, 0, stream>>>(c_sum, e_ctx, cg, cb, cw1, cb1, cw2, cb2, chh, 10);
  lin4_kernel<<<256, 256, 0, stream>>>(ahh, rw1, rg, 0, Ya);
  lin4_kernel<<<16, 256, 0, stream>>>(qh, rw1, rg, 512, Yq);

  static const size_t MAIN_SMEM = 5120 + 131072;  // 136192 B
  hipFuncSetAttribute((const void*)main_kernel,
                      hipFuncAttributeMaxDynamicSharedMemorySize, (int)MAIN_SMEM);
  main_kernel<<<1024, 512, MAIN_SMEM, stream>>>(ahh, qh, chh, WT, Ya, Yq, S1, B1,
                                                rb1, rw2, rb2, c_mass, out);
}